// Round 10
// baseline (244.468 us; speedup 1.0000x reference)
//
#include <hip/hip_runtime.h>

// SGConv (k=1) + Linear, fused pipeline:
//   1) deg8[x][dst]++               (XCD-privatized histogram, x=(e>>8)&7)
//   2) deg = sum_x deg8             (reduce)
//   3) exclusive scan(deg)          (3-phase; emits norm[])
//   4) curX[x][n] = row_start[n] + prefix_x(deg8)  (per-partition cursors)
//   5) counting-sort edges by dst   (atomics on XCD-local cursor plane)
//   6) xs = bf16(x * norm)          (stream pass)
//   7) h2 = norm * sum_e xs[src_e]  (wave/node, bf16 gather + fp32 accum)
//      -> h2 written PRE-SPLIT as bf16 hi/lo arrays
//   8) out = relu(relu(h2 @ Wc^T + bc) @ Wl^T + bl)   (MFMA, 2-way bf16 split)

#define D 128
#define SCAN_TILE 1024  // 256 threads * 4 elements
#define NPART 8

typedef __attribute__((ext_vector_type(8))) short short8;
typedef __attribute__((ext_vector_type(4))) float f32x4;

__device__ __forceinline__ unsigned short f2bf(float f) {
    union { float f; unsigned u; } c; c.f = f;
    unsigned u = c.u;
    unsigned r = u + 0x7FFFu + ((u >> 16) & 1u);  // RNE
    return (unsigned short)(r >> 16);
}
__device__ __forceinline__ float bf2f(unsigned short b) {
    union { unsigned u; float f; } c; c.u = ((unsigned)b) << 16;
    return c.f;
}

// XCD-privatized histogram: partition x = blockIdx&7 (== (e>>8)&7), one edge/thread
__global__ __launch_bounds__(256) void degree_kernel(const int* __restrict__ dst,
                                                     int* __restrict__ deg8, int N, int E) {
    int e = blockIdx.x * blockDim.x + threadIdx.x;
    if (e < E) atomicAdd(&deg8[(blockIdx.x & (NPART - 1)) * N + dst[e]], 1);
}

// deg[n] = sum_x deg8[x][n]   (int4 over nodes, coalesced plane reads)
__global__ __launch_bounds__(256) void reduce_deg_kernel(const int* __restrict__ deg8,
                                                         int* __restrict__ deg, int N) {
    int base = (blockIdx.x * blockDim.x + threadIdx.x) << 2;
    if (base >= N) return;
    int4 s = make_int4(0, 0, 0, 0);
    #pragma unroll
    for (int x = 0; x < NPART; ++x) {
        int4 v = *(const int4*)(deg8 + (size_t)x * N + base);  // N multiple of 4
        s.x += v.x; s.y += v.y; s.z += v.z; s.w += v.w;
    }
    *(int4*)(deg + base) = s;
}

// ---- 3-phase exclusive scan over deg[0..N) -> row_start[0..N], norm ----
__global__ __launch_bounds__(256) void scan_partial_kernel(const int* __restrict__ deg,
                                                           int* __restrict__ blockSums, int N) {
    int tid = threadIdx.x;
    int base = blockIdx.x * SCAN_TILE + (tid << 2);
    int4 v = make_int4(0, 0, 0, 0);
    if (base + 3 < N) v = *(const int4*)(deg + base);
    else {
        if (base + 0 < N) v.x = deg[base + 0];
        if (base + 1 < N) v.y = deg[base + 1];
        if (base + 2 < N) v.z = deg[base + 2];
        if (base + 3 < N) v.w = deg[base + 3];
    }
    int s = v.x + v.y + v.z + v.w;
    for (int off = 32; off; off >>= 1) s += __shfl_down(s, off, 64);
    __shared__ int ws[4];
    if ((tid & 63) == 0) ws[tid >> 6] = s;
    __syncthreads();
    if (tid == 0) blockSums[blockIdx.x] = ws[0] + ws[1] + ws[2] + ws[3];
}

__global__ __launch_bounds__(256) void scan_blocksums_kernel(int* __restrict__ blockSums, int B) {
    __shared__ int s[256];
    int tid = threadIdx.x;
    int v = (tid < B) ? blockSums[tid] : 0;
    s[tid] = v;
    __syncthreads();
    for (int off = 1; off < 256; off <<= 1) {
        int u = (tid >= off) ? s[tid - off] : 0;
        __syncthreads();
        s[tid] += u;
        __syncthreads();
    }
    if (tid < B) blockSums[tid] = (tid == 0) ? 0 : s[tid - 1];
}

__global__ __launch_bounds__(256) void scan_final_kernel(
    const int* __restrict__ deg, const int* __restrict__ blockSums,
    int* __restrict__ row_start, float* __restrict__ norm, int N, int E) {
    int tid = threadIdx.x;
    int base = blockIdx.x * SCAN_TILE + (tid << 2);
    int4 v = make_int4(0, 0, 0, 0);
    if (base + 3 < N) v = *(const int4*)(deg + base);
    else {
        if (base + 0 < N) v.x = deg[base + 0];
        if (base + 1 < N) v.y = deg[base + 1];
        if (base + 2 < N) v.z = deg[base + 2];
        if (base + 3 < N) v.w = deg[base + 3];
    }
    int local = v.x + v.y + v.z + v.w;
    int lane = tid & 63, w = tid >> 6;
    int inc = local;
    for (int off = 1; off < 64; off <<= 1) {
        int u = __shfl_up(inc, off, 64);
        if (lane >= off) inc += u;
    }
    __shared__ int wsum[4];
    if (lane == 63) wsum[w] = inc;
    __syncthreads();
    int woff = 0;
    for (int i = 0; i < w; ++i) woff += wsum[i];
    int ex = (inc - local) + woff + blockSums[blockIdx.x];
    int4 rs;
    rs.x = ex;
    rs.y = rs.x + v.x;
    rs.z = rs.y + v.y;
    rs.w = rs.z + v.z;
    float4 nm;
    nm.x = rsqrtf(fmaxf((float)v.x, 1.0f));
    nm.y = rsqrtf(fmaxf((float)v.y, 1.0f));
    nm.z = rsqrtf(fmaxf((float)v.z, 1.0f));
    nm.w = rsqrtf(fmaxf((float)v.w, 1.0f));
    if (base + 3 < N) {
        *(int4*)(row_start + base) = rs;
        *(float4*)(norm + base) = nm;
    } else {
        if (base + 0 < N) { row_start[base + 0] = rs.x; norm[base + 0] = nm.x; }
        if (base + 1 < N) { row_start[base + 1] = rs.y; norm[base + 1] = nm.y; }
        if (base + 2 < N) { row_start[base + 2] = rs.z; norm[base + 2] = nm.z; }
    }
    if (blockIdx.x == 0 && tid == 0) row_start[N] = E;
}

// curX[x][n] = row_start[n] + sum_{x'<x} deg8[x'][n]   (int4 over nodes)
__global__ __launch_bounds__(256) void cursor_init_kernel(
    const int* __restrict__ deg8, const int* __restrict__ row_start,
    int* __restrict__ curX, int N) {
    int base = (blockIdx.x * blockDim.x + threadIdx.x) << 2;
    if (base >= N) return;
    int4 run = *(const int4*)(row_start + base);
    #pragma unroll
    for (int x = 0; x < NPART; ++x) {
        *(int4*)(curX + (size_t)x * N + base) = run;
        int4 v = *(const int4*)(deg8 + (size_t)x * N + base);
        run.x += v.x; run.y += v.y; run.z += v.z; run.w += v.w;
    }
}

// counting-sort scatter: atomic on XCD-local cursor plane; u16 payload
__global__ __launch_bounds__(256) void binning_kernel(
    const int* __restrict__ src, const int* __restrict__ dst,
    int* __restrict__ curX, unsigned short* __restrict__ sorted16, int N, int E) {
    int e = blockIdx.x * blockDim.x + threadIdx.x;
    if (e < E) {
        int d = dst[e];
        int s = src[e];
        int p = atomicAdd(&curX[(blockIdx.x & (NPART - 1)) * N + d], 1);
        sorted16[p] = (unsigned short)s;
    }
}

// xs = bf16(x * norm[row])  (reads float4, writes ushort4 = 8B/lane)
__global__ void scale_kernel(const float* __restrict__ x, const float* __restrict__ norm,
                             unsigned short* __restrict__ xsb, int N) {
    int idx = blockIdx.x * blockDim.x + threadIdx.x;
    int total = N * (D / 4);
    if (idx >= total) return;
    int row = idx >> 5;  // D/4 == 32
    float nrm = norm[row];
    float4 v = ((const float4*)x)[idx];
    ushort4 o;
    o.x = f2bf(v.x * nrm);
    o.y = f2bf(v.y * nrm);
    o.z = f2bf(v.z * nrm);
    o.w = f2bf(v.w * nrm);
    ((ushort4*)xsb)[idx] = o;
}

__device__ __forceinline__ void addbf4(float4& a, ushort4 u) {
    a.x += bf2f(u.x);
    a.y += bf2f(u.y);
    a.z += bf2f(u.z);
    a.w += bf2f(u.w);
}

// wave per destination node; bf16 gather (256B/row), fp32 accum; 2 rows in
// flight via lane-halves, 8 outstanding 8B loads/lane; outputs pre-split bf16
__global__ __launch_bounds__(256) void aggregate_kernel(
    const unsigned short* __restrict__ xsb, const unsigned short* __restrict__ sorted16,
    const int* __restrict__ row_start, const float* __restrict__ norm,
    unsigned short* __restrict__ h2hi, unsigned short* __restrict__ h2lo, int N) {
    int wave = (int)((blockIdx.x * blockDim.x + threadIdx.x) >> 6);
    int lane = threadIdx.x & 63;
    if (wave >= N) return;
    int s = row_start[wave];
    int t = row_start[wave + 1];
    int c4 = (lane & 31) << 2;   // element column (4 bf16 per lane)
    int half = lane >> 5;        // which edge of the pair
    float4 acc = make_float4(0.f, 0.f, 0.f, 0.f);
    for (int base = s; base < t; base += 64) {
        int cnt = min(64, t - base);
        int my = (lane < cnt) ? (int)sorted16[base + lane] : 0;
        int j = 0;
        for (; j + 15 < cnt; j += 16) {  // 8 outstanding 8B loads per lane
            int i0 = __shfl(my, j + 0 + half, 64);
            int i1 = __shfl(my, j + 2 + half, 64);
            int i2 = __shfl(my, j + 4 + half, 64);
            int i3 = __shfl(my, j + 6 + half, 64);
            int i4 = __shfl(my, j + 8 + half, 64);
            int i5 = __shfl(my, j + 10 + half, 64);
            int i6 = __shfl(my, j + 12 + half, 64);
            int i7 = __shfl(my, j + 14 + half, 64);
            ushort4 u0 = *(const ushort4*)(xsb + (size_t)i0 * D + c4);
            ushort4 u1 = *(const ushort4*)(xsb + (size_t)i1 * D + c4);
            ushort4 u2 = *(const ushort4*)(xsb + (size_t)i2 * D + c4);
            ushort4 u3 = *(const ushort4*)(xsb + (size_t)i3 * D + c4);
            ushort4 u4 = *(const ushort4*)(xsb + (size_t)i4 * D + c4);
            ushort4 u5 = *(const ushort4*)(xsb + (size_t)i5 * D + c4);
            ushort4 u6 = *(const ushort4*)(xsb + (size_t)i6 * D + c4);
            ushort4 u7 = *(const ushort4*)(xsb + (size_t)i7 * D + c4);
            addbf4(acc, u0); addbf4(acc, u1); addbf4(acc, u2); addbf4(acc, u3);
            addbf4(acc, u4); addbf4(acc, u5); addbf4(acc, u6); addbf4(acc, u7);
        }
        for (; j + 1 < cnt; j += 2) {
            int i0 = __shfl(my, j + half, 64);
            ushort4 u0 = *(const ushort4*)(xsb + (size_t)i0 * D + c4);
            addbf4(acc, u0);
        }
        if (j < cnt) {  // odd leftover edge: half 0 only
            int i0 = __shfl(my, j, 64);
            if (half == 0) {
                ushort4 u0 = *(const ushort4*)(xsb + (size_t)i0 * D + c4);
                addbf4(acc, u0);
            }
        }
    }
    // combine the two halves
    acc.x += __shfl_xor(acc.x, 32, 64);
    acc.y += __shfl_xor(acc.y, 32, 64);
    acc.z += __shfl_xor(acc.z, 32, 64);
    acc.w += __shfl_xor(acc.w, 32, 64);
    if (half == 0) {
        float nrm = norm[wave];
        float o[4] = {acc.x * nrm, acc.y * nrm, acc.z * nrm, acc.w * nrm};
        ushort4 hv, lv;
        unsigned short* hp = (unsigned short*)&hv;
        unsigned short* lp = (unsigned short*)&lv;
        #pragma unroll
        for (int q = 0; q < 4; ++q) {
            unsigned short h = f2bf(o[q]);
            float r = o[q] - bf2f(h);
            hp[q] = h;
            lp[q] = f2bf(r);
        }
        *(ushort4*)(h2hi + (size_t)wave * D + c4) = hv;
        *(ushort4*)(h2lo + (size_t)wave * D + c4) = lv;
    }
}

// ---------------- MFMA MLP (2-way split) ----------------
// weight prep: split each fp32 into hi/lo bf16
__global__ __launch_bounds__(256) void prep_w_kernel(
    const float* __restrict__ wc, const float* __restrict__ wl,
    unsigned short* __restrict__ w1c, unsigned short* __restrict__ w2c,
    unsigned short* __restrict__ w1l, unsigned short* __restrict__ w2l) {
    int idx = blockIdx.x * 256 + threadIdx.x;  // 0..32767
    const float* src = (idx < 16384) ? wc : wl;
    int j = idx & 16383;
    float x = src[j];
    unsigned short c1 = f2bf(x);
    float r = x - bf2f(c1);
    unsigned short c2 = f2bf(r);
    if (idx < 16384) { w1c[j] = c1; w2c[j] = c2; }
    else             { w1l[j] = c1; w2l[j] = c2; }
}

// LDS tiles: bf16 [64 rows][128], 16B slots swizzled: slot' = slot ^ (row&7)
__device__ __forceinline__ void layer_bf(
    const unsigned short* shi, const unsigned short* slo,
    const unsigned short* __restrict__ w1, const unsigned short* __restrict__ w2,
    const float* __restrict__ bias,
    f32x4 acc[2][4], int wr0, int wc0, int lm, int lg) {
    #pragma unroll
    for (int mt = 0; mt < 2; ++mt)
        #pragma unroll
        for (int nt = 0; nt < 4; ++nt) {
            float b = bias[wc0 + nt * 16 + lm];
            acc[mt][nt] = (f32x4){b, b, b, b};
        }
    #pragma unroll
    for (int k0 = 0; k0 < 128; k0 += 32) {
        short8 ahi[2], alo[2];
        #pragma unroll
        for (int mt = 0; mt < 2; ++mt) {
            int row = wr0 + mt * 16 + lm;
            int slot = (k0 >> 3) + lg;
            int off = row * 128 + (((slot) ^ (row & 7)) << 3);
            ahi[mt] = *(const short8*)(shi + off);
            alo[mt] = *(const short8*)(slo + off);
        }
        #pragma unroll
        for (int nt = 0; nt < 4; ++nt) {
            int widx = (wc0 + nt * 16 + lm) * 128 + k0 + lg * 8;
            short8 bhi = *(const short8*)(w1 + widx);
            short8 blo = *(const short8*)(w2 + widx);
            #pragma unroll
            for (int mt = 0; mt < 2; ++mt) {
                f32x4 c = acc[mt][nt];
                c = __builtin_amdgcn_mfma_f32_16x16x32_bf16(ahi[mt], blo, c, 0, 0, 0);
                c = __builtin_amdgcn_mfma_f32_16x16x32_bf16(alo[mt], bhi, c, 0, 0, 0);
                c = __builtin_amdgcn_mfma_f32_16x16x32_bf16(ahi[mt], bhi, c, 0, 0, 0);
                acc[mt][nt] = c;
            }
        }
    }
}

// relu + split into swizzled bf16 LDS (C layout: col=lane&15, row=(lane>>4)*4+reg)
__device__ __forceinline__ void store_bf(
    unsigned short* shi, unsigned short* slo,
    f32x4 acc[2][4], int wr0, int wc0, int lm, int lg) {
    #pragma unroll
    for (int mt = 0; mt < 2; ++mt)
        #pragma unroll
        for (int nt = 0; nt < 4; ++nt)
            #pragma unroll
            for (int j = 0; j < 4; ++j) {
                int row = wr0 + mt * 16 + lg * 4 + j;
                int col = wc0 + nt * 16 + lm;
                float v = fmaxf(acc[mt][nt][j], 0.0f);
                unsigned short h = f2bf(v);
                float r = v - bf2f(h);
                int off = row * 128 + (((col >> 3) ^ (row & 7)) << 3) + (col & 7);
                shi[off] = h;
                slo[off] = f2bf(r);
            }
}

__global__ __launch_bounds__(256, 2) void mlp_mfma_kernel(
    const unsigned short* __restrict__ h2hi, const unsigned short* __restrict__ h2lo,
    const unsigned short* __restrict__ w1c, const unsigned short* __restrict__ w2c,
    const float* __restrict__ bc,
    const unsigned short* __restrict__ w1l, const unsigned short* __restrict__ w2l,
    const float* __restrict__ bl,
    float* __restrict__ out, int N) {
    __shared__ unsigned short shi[64 * 128];  // 16 KB
    __shared__ unsigned short slo[64 * 128];  // 16 KB
    int tid = threadIdx.x;
    int row0 = blockIdx.x * 64;

    // stage pre-split h2 (coalesced 16B global loads -> swizzled LDS slots)
    #pragma unroll
    for (int i = 0; i < 4; ++i) {
        int f = i * 256 + tid;            // slot id 0..1023
        int r = f >> 4, sl = f & 15;
        int grow = row0 + r;
        short8 vh = (short8){0,0,0,0,0,0,0,0};
        short8 vl = (short8){0,0,0,0,0,0,0,0};
        if (grow < N) {
            vh = *(const short8*)(h2hi + (size_t)grow * D + sl * 8);
            vl = *(const short8*)(h2lo + (size_t)grow * D + sl * 8);
        }
        int off = r * 128 + ((sl ^ (r & 7)) << 3);
        *(short8*)(shi + off) = vh;
        *(short8*)(slo + off) = vl;
    }
    __syncthreads();

    int w = tid >> 6, lane = tid & 63;
    int lm = lane & 15, lg = lane >> 4;
    int wr0 = (w >> 1) * 32, wc0 = (w & 1) * 64;

    f32x4 acc[2][4];

    layer_bf(shi, slo, w1c, w2c, bc, acc, wr0, wc0, lm, lg);
    __syncthreads();                   // all reads of tiles done
    store_bf(shi, slo, acc, wr0, wc0, lm, lg);
    __syncthreads();

    layer_bf(shi, slo, w1l, w2l, bl, acc, wr0, wc0, lm, lg);

    // direct relu + store to global (64B-granular coalescing per 16-lane group)
    #pragma unroll
    for (int mt = 0; mt < 2; ++mt)
        #pragma unroll
        for (int j = 0; j < 4; ++j) {
            int row = row0 + wr0 + mt * 16 + lg * 4 + j;
            if (row < N) {
                #pragma unroll
                for (int nt = 0; nt < 4; ++nt)
                    out[(size_t)row * D + wc0 + nt * 16 + lm] = fmaxf(acc[mt][nt][j], 0.0f);
            }
        }
}

extern "C" void kernel_launch(void* const* d_in, const int* in_sizes, int n_in,
                              void* d_out, int out_size, void* d_ws, size_t ws_size,
                              hipStream_t stream) {
    const float* x      = (const float*)d_in[0];
    const int*   src    = (const int*)d_in[1];
    const int*   dst    = (const int*)d_in[2];
    const float* wc     = (const float*)d_in[3];
    const float* bc     = (const float*)d_in[4];
    const float* wl     = (const float*)d_in[5];
    const float* bl     = (const float*)d_in[6];
    float* out = (float*)d_out;

    int N = in_sizes[0] / D;
    int E = in_sizes[1];

    // workspace carve-up (256B aligned)
    size_t off = 0;
    auto carve = [&](size_t bytes) -> void* {
        void* p = (char*)d_ws + off;
        off += (bytes + 255) & ~(size_t)255;
        return p;
    };
    unsigned short* xsb       = (unsigned short*)carve((size_t)N * D * 2);
    unsigned short* h2hi      = (unsigned short*)carve((size_t)N * D * 2);
    unsigned short* h2lo      = (unsigned short*)carve((size_t)N * D * 2);
    int*            deg8      = (int*)carve((size_t)NPART * N * 4);
    int*            deg       = (int*)carve((size_t)N * 4);
    int*            row_start = (int*)carve((size_t)(N + 1) * 4);
    int*            curX      = (int*)carve((size_t)NPART * N * 4);
    float*          norm      = (float*)carve((size_t)N * 4);
    int*            blockSums = (int*)carve(1024 * 4);
    unsigned short* sorted16  = (unsigned short*)carve((size_t)E * 2);
    unsigned short* w1c = (unsigned short*)carve(16384 * 2);
    unsigned short* w2c = (unsigned short*)carve(16384 * 2);
    unsigned short* w1l = (unsigned short*)carve(16384 * 2);
    unsigned short* w2l = (unsigned short*)carve(16384 * 2);
    (void)ws_size;

    hipMemsetAsync(deg8, 0, (size_t)NPART * N * 4, stream);

    int nScanBlocks = (N + SCAN_TILE - 1) / SCAN_TILE;

    prep_w_kernel<<<128, 256, 0, stream>>>(wc, wl, w1c, w2c, w1l, w2l);
    degree_kernel<<<(E + 255) / 256, 256, 0, stream>>>(dst, deg8, N, E);
    reduce_deg_kernel<<<(N / 4 + 255) / 256, 256, 0, stream>>>(deg8, deg, N);
    scan_partial_kernel<<<nScanBlocks, 256, 0, stream>>>(deg, blockSums, N);
    scan_blocksums_kernel<<<1, 256, 0, stream>>>(blockSums, nScanBlocks);
    scan_final_kernel<<<nScanBlocks, 256, 0, stream>>>(deg, blockSums, row_start, norm, N, E);
    cursor_init_kernel<<<(N / 4 + 255) / 256, 256, 0, stream>>>(deg8, row_start, curX, N);
    binning_kernel<<<(E + 255) / 256, 256, 0, stream>>>(src, dst, curX, sorted16, N, E);
    {
        int total = N * (D / 4);
        scale_kernel<<<(total + 255) / 256, 256, 0, stream>>>(x, norm, xsb, N);
    }
    aggregate_kernel<<<(N + 3) / 4, 256, 0, stream>>>(xsb, sorted16, row_start, norm, h2hi, h2lo, N);
    mlp_mfma_kernel<<<(N + 63) / 64, 256, 0, stream>>>(h2hi, h2lo, w1c, w2c, bc, w1l, w2l, bl, out, N);
}

// Round 12
// 213.601 us; speedup vs baseline: 1.1445x; 1.1445x over previous
//
#include <hip/hip_runtime.h>

// SGConv (k=1) + Linear, fused pipeline:
//   1) rank16[e] = degp[dst]++      (ONE atomic pass; 64B-padded counters)
//   2) exclusive scan(degp strided) (3-phase; emits norm[])
//   3) sorted16[row_start[d]+rank16[e]] = src[e]   (atomic-FREE scatter)
//   4) xs = bf16(x * norm)          (stream pass)
//   5) h2 = norm * sum_e xs[src_e]  (wave/node, bf16 gather + fp32 accum)
//      -> h2 written PRE-SPLIT as bf16 hi/lo arrays
//   6) out = relu(relu(h2 @ Wc^T + bc) @ Wl^T + bl)   (MFMA, 2-way bf16 split)

#define D 128
#define SCAN_TILE 1024  // 256 threads * 4 elements
#define PAD 16          // one counter per 64B line

typedef __attribute__((ext_vector_type(8))) short short8;
typedef __attribute__((ext_vector_type(4))) float f32x4;

__device__ __forceinline__ unsigned short f2bf(float f) {
    union { float f; unsigned u; } c; c.f = f;
    unsigned u = c.u;
    unsigned r = u + 0x7FFFu + ((u >> 16) & 1u);  // RNE
    return (unsigned short)(r >> 16);
}
__device__ __forceinline__ float bf2f(unsigned short b) {
    union { unsigned u; float f; } c; c.u = ((unsigned)b) << 16;
    return c.f;
}

// one atomic pass: histogram AND stable rank (padded counters: 1 per 64B line)
__global__ __launch_bounds__(256) void degree_rank_kernel(
    const int* __restrict__ dst, int* __restrict__ degp,
    unsigned short* __restrict__ rank16, int E) {
    int e = blockIdx.x * blockDim.x + threadIdx.x;
    if (e < E) {
        int p = atomicAdd(&degp[dst[e] * PAD], 1);
        rank16[e] = (unsigned short)p;
    }
}

// ---- 3-phase exclusive scan over degp (strided) -> row_start[0..N], norm ----
__global__ __launch_bounds__(256) void scan_partial_kernel(const int* __restrict__ degp,
                                                           int* __restrict__ blockSums, int N) {
    int tid = threadIdx.x;
    int base = blockIdx.x * SCAN_TILE + (tid << 2);
    int4 v = make_int4(0, 0, 0, 0);
    if (base + 0 < N) v.x = degp[(base + 0) * PAD];
    if (base + 1 < N) v.y = degp[(base + 1) * PAD];
    if (base + 2 < N) v.z = degp[(base + 2) * PAD];
    if (base + 3 < N) v.w = degp[(base + 3) * PAD];
    int s = v.x + v.y + v.z + v.w;
    for (int off = 32; off; off >>= 1) s += __shfl_down(s, off, 64);
    __shared__ int ws[4];
    if ((tid & 63) == 0) ws[tid >> 6] = s;
    __syncthreads();
    if (tid == 0) blockSums[blockIdx.x] = ws[0] + ws[1] + ws[2] + ws[3];
}

__global__ __launch_bounds__(256) void scan_blocksums_kernel(int* __restrict__ blockSums, int B) {
    __shared__ int s[256];
    int tid = threadIdx.x;
    int v = (tid < B) ? blockSums[tid] : 0;
    s[tid] = v;
    __syncthreads();
    for (int off = 1; off < 256; off <<= 1) {
        int u = (tid >= off) ? s[tid - off] : 0;
        __syncthreads();
        s[tid] += u;
        __syncthreads();
    }
    if (tid < B) blockSums[tid] = (tid == 0) ? 0 : s[tid - 1];
}

__global__ __launch_bounds__(256) void scan_final_kernel(
    const int* __restrict__ degp, const int* __restrict__ blockSums,
    int* __restrict__ row_start, float* __restrict__ norm, int N, int E) {
    int tid = threadIdx.x;
    int base = blockIdx.x * SCAN_TILE + (tid << 2);
    int4 v = make_int4(0, 0, 0, 0);
    if (base + 0 < N) v.x = degp[(base + 0) * PAD];
    if (base + 1 < N) v.y = degp[(base + 1) * PAD];
    if (base + 2 < N) v.z = degp[(base + 2) * PAD];
    if (base + 3 < N) v.w = degp[(base + 3) * PAD];
    int local = v.x + v.y + v.z + v.w;
    int lane = tid & 63, w = tid >> 6;
    int inc = local;
    for (int off = 1; off < 64; off <<= 1) {
        int u = __shfl_up(inc, off, 64);
        if (lane >= off) inc += u;
    }
    __shared__ int wsum[4];
    if (lane == 63) wsum[w] = inc;
    __syncthreads();
    int woff = 0;
    for (int i = 0; i < w; ++i) woff += wsum[i];
    int ex = (inc - local) + woff + blockSums[blockIdx.x];
    int4 rs;
    rs.x = ex;
    rs.y = rs.x + v.x;
    rs.z = rs.y + v.y;
    rs.w = rs.z + v.z;
    float4 nm;
    nm.x = rsqrtf(fmaxf((float)v.x, 1.0f));
    nm.y = rsqrtf(fmaxf((float)v.y, 1.0f));
    nm.z = rsqrtf(fmaxf((float)v.z, 1.0f));
    nm.w = rsqrtf(fmaxf((float)v.w, 1.0f));
    if (base + 3 < N) {
        *(int4*)(row_start + base) = rs;
        *(float4*)(norm + base) = nm;
    } else {
        if (base + 0 < N) { row_start[base + 0] = rs.x; norm[base + 0] = nm.x; }
        if (base + 1 < N) { row_start[base + 1] = rs.y; norm[base + 1] = nm.y; }
        if (base + 2 < N) { row_start[base + 2] = rs.z; norm[base + 2] = nm.z; }
    }
    if (blockIdx.x == 0 && tid == 0) row_start[N] = E;
}

// atomic-free scatter: position = row_start[dst] + rank
__global__ __launch_bounds__(256) void scatter_kernel(
    const int* __restrict__ src, const int* __restrict__ dst,
    const unsigned short* __restrict__ rank16, const int* __restrict__ row_start,
    unsigned short* __restrict__ sorted16, int E) {
    int e = blockIdx.x * blockDim.x + threadIdx.x;
    if (e < E) {
        int d = dst[e];
        int p = row_start[d] + (int)rank16[e];
        sorted16[p] = (unsigned short)src[e];
    }
}

// xs = bf16(x * norm[row])  (reads float4, writes ushort4 = 8B/lane)
__global__ void scale_kernel(const float* __restrict__ x, const float* __restrict__ norm,
                             unsigned short* __restrict__ xsb, int N) {
    int idx = blockIdx.x * blockDim.x + threadIdx.x;
    int total = N * (D / 4);
    if (idx >= total) return;
    int row = idx >> 5;  // D/4 == 32
    float nrm = norm[row];
    float4 v = ((const float4*)x)[idx];
    ushort4 o;
    o.x = f2bf(v.x * nrm);
    o.y = f2bf(v.y * nrm);
    o.z = f2bf(v.z * nrm);
    o.w = f2bf(v.w * nrm);
    ((ushort4*)xsb)[idx] = o;
}

__device__ __forceinline__ void addbf4(float4& a, ushort4 u) {
    a.x += bf2f(u.x);
    a.y += bf2f(u.y);
    a.z += bf2f(u.z);
    a.w += bf2f(u.w);
}

// wave per destination node; bf16 gather (256B/row), fp32 accum; 2 rows in
// flight via lane-halves, 8 outstanding 8B loads/lane; outputs pre-split bf16
__global__ __launch_bounds__(256) void aggregate_kernel(
    const unsigned short* __restrict__ xsb, const unsigned short* __restrict__ sorted16,
    const int* __restrict__ row_start, const float* __restrict__ norm,
    unsigned short* __restrict__ h2hi, unsigned short* __restrict__ h2lo, int N) {
    int wave = (int)((blockIdx.x * blockDim.x + threadIdx.x) >> 6);
    int lane = threadIdx.x & 63;
    if (wave >= N) return;
    int s = row_start[wave];
    int t = row_start[wave + 1];
    int c4 = (lane & 31) << 2;   // element column (4 bf16 per lane)
    int half = lane >> 5;        // which edge of the pair
    float4 acc = make_float4(0.f, 0.f, 0.f, 0.f);
    for (int base = s; base < t; base += 64) {
        int cnt = min(64, t - base);
        int my = (lane < cnt) ? (int)sorted16[base + lane] : 0;
        int j = 0;
        for (; j + 15 < cnt; j += 16) {  // 8 outstanding 8B loads per lane
            int i0 = __shfl(my, j + 0 + half, 64);
            int i1 = __shfl(my, j + 2 + half, 64);
            int i2 = __shfl(my, j + 4 + half, 64);
            int i3 = __shfl(my, j + 6 + half, 64);
            int i4 = __shfl(my, j + 8 + half, 64);
            int i5 = __shfl(my, j + 10 + half, 64);
            int i6 = __shfl(my, j + 12 + half, 64);
            int i7 = __shfl(my, j + 14 + half, 64);
            ushort4 u0 = *(const ushort4*)(xsb + (size_t)i0 * D + c4);
            ushort4 u1 = *(const ushort4*)(xsb + (size_t)i1 * D + c4);
            ushort4 u2 = *(const ushort4*)(xsb + (size_t)i2 * D + c4);
            ushort4 u3 = *(const ushort4*)(xsb + (size_t)i3 * D + c4);
            ushort4 u4 = *(const ushort4*)(xsb + (size_t)i4 * D + c4);
            ushort4 u5 = *(const ushort4*)(xsb + (size_t)i5 * D + c4);
            ushort4 u6 = *(const ushort4*)(xsb + (size_t)i6 * D + c4);
            ushort4 u7 = *(const ushort4*)(xsb + (size_t)i7 * D + c4);
            addbf4(acc, u0); addbf4(acc, u1); addbf4(acc, u2); addbf4(acc, u3);
            addbf4(acc, u4); addbf4(acc, u5); addbf4(acc, u6); addbf4(acc, u7);
        }
        for (; j + 1 < cnt; j += 2) {
            int i0 = __shfl(my, j + half, 64);
            ushort4 u0 = *(const ushort4*)(xsb + (size_t)i0 * D + c4);
            addbf4(acc, u0);
        }
        if (j < cnt) {  // odd leftover edge: half 0 only
            int i0 = __shfl(my, j, 64);
            if (half == 0) {
                ushort4 u0 = *(const ushort4*)(xsb + (size_t)i0 * D + c4);
                addbf4(acc, u0);
            }
        }
    }
    // combine the two halves
    acc.x += __shfl_xor(acc.x, 32, 64);
    acc.y += __shfl_xor(acc.y, 32, 64);
    acc.z += __shfl_xor(acc.z, 32, 64);
    acc.w += __shfl_xor(acc.w, 32, 64);
    if (half == 0) {
        float nrm = norm[wave];
        float o[4] = {acc.x * nrm, acc.y * nrm, acc.z * nrm, acc.w * nrm};
        ushort4 hv, lv;
        unsigned short* hp = (unsigned short*)&hv;
        unsigned short* lp = (unsigned short*)&lv;
        #pragma unroll
        for (int q = 0; q < 4; ++q) {
            unsigned short h = f2bf(o[q]);
            float r = o[q] - bf2f(h);
            hp[q] = h;
            lp[q] = f2bf(r);
        }
        *(ushort4*)(h2hi + (size_t)wave * D + c4) = hv;
        *(ushort4*)(h2lo + (size_t)wave * D + c4) = lv;
    }
}

// ---------------- MFMA MLP (2-way split) ----------------
// weight prep: split each fp32 into hi/lo bf16
__global__ __launch_bounds__(256) void prep_w_kernel(
    const float* __restrict__ wc, const float* __restrict__ wl,
    unsigned short* __restrict__ w1c, unsigned short* __restrict__ w2c,
    unsigned short* __restrict__ w1l, unsigned short* __restrict__ w2l) {
    int idx = blockIdx.x * 256 + threadIdx.x;  // 0..32767
    const float* src = (idx < 16384) ? wc : wl;
    int j = idx & 16383;
    float x = src[j];
    unsigned short c1 = f2bf(x);
    float r = x - bf2f(c1);
    unsigned short c2 = f2bf(r);
    if (idx < 16384) { w1c[j] = c1; w2c[j] = c2; }
    else             { w1l[j] = c1; w2l[j] = c2; }
}

// LDS tiles: bf16 [64 rows][128], 16B slots swizzled: slot' = slot ^ (row&7)
__device__ __forceinline__ void layer_bf(
    const unsigned short* shi, const unsigned short* slo,
    const unsigned short* __restrict__ w1, const unsigned short* __restrict__ w2,
    const float* __restrict__ bias,
    f32x4 acc[2][4], int wr0, int wc0, int lm, int lg) {
    #pragma unroll
    for (int mt = 0; mt < 2; ++mt)
        #pragma unroll
        for (int nt = 0; nt < 4; ++nt) {
            float b = bias[wc0 + nt * 16 + lm];
            acc[mt][nt] = (f32x4){b, b, b, b};
        }
    #pragma unroll
    for (int k0 = 0; k0 < 128; k0 += 32) {
        short8 ahi[2], alo[2];
        #pragma unroll
        for (int mt = 0; mt < 2; ++mt) {
            int row = wr0 + mt * 16 + lm;
            int slot = (k0 >> 3) + lg;
            int off = row * 128 + (((slot) ^ (row & 7)) << 3);
            ahi[mt] = *(const short8*)(shi + off);
            alo[mt] = *(const short8*)(slo + off);
        }
        #pragma unroll
        for (int nt = 0; nt < 4; ++nt) {
            int widx = (wc0 + nt * 16 + lm) * 128 + k0 + lg * 8;
            short8 bhi = *(const short8*)(w1 + widx);
            short8 blo = *(const short8*)(w2 + widx);
            #pragma unroll
            for (int mt = 0; mt < 2; ++mt) {
                f32x4 c = acc[mt][nt];
                c = __builtin_amdgcn_mfma_f32_16x16x32_bf16(ahi[mt], blo, c, 0, 0, 0);
                c = __builtin_amdgcn_mfma_f32_16x16x32_bf16(alo[mt], bhi, c, 0, 0, 0);
                c = __builtin_amdgcn_mfma_f32_16x16x32_bf16(ahi[mt], bhi, c, 0, 0, 0);
                acc[mt][nt] = c;
            }
        }
    }
}

// relu + split into swizzled bf16 LDS (C layout: col=lane&15, row=(lane>>4)*4+reg)
__device__ __forceinline__ void store_bf(
    unsigned short* shi, unsigned short* slo,
    f32x4 acc[2][4], int wr0, int wc0, int lm, int lg) {
    #pragma unroll
    for (int mt = 0; mt < 2; ++mt)
        #pragma unroll
        for (int nt = 0; nt < 4; ++nt)
            #pragma unroll
            for (int j = 0; j < 4; ++j) {
                int row = wr0 + mt * 16 + lg * 4 + j;
                int col = wc0 + nt * 16 + lm;
                float v = fmaxf(acc[mt][nt][j], 0.0f);
                unsigned short h = f2bf(v);
                float r = v - bf2f(h);
                int off = row * 128 + (((col >> 3) ^ (row & 7)) << 3) + (col & 7);
                shi[off] = h;
                slo[off] = f2bf(r);
            }
}

__global__ __launch_bounds__(256, 2) void mlp_mfma_kernel(
    const unsigned short* __restrict__ h2hi, const unsigned short* __restrict__ h2lo,
    const unsigned short* __restrict__ w1c, const unsigned short* __restrict__ w2c,
    const float* __restrict__ bc,
    const unsigned short* __restrict__ w1l, const unsigned short* __restrict__ w2l,
    const float* __restrict__ bl,
    float* __restrict__ out, int N) {
    __shared__ unsigned short shi[64 * 128];  // 16 KB
    __shared__ unsigned short slo[64 * 128];  // 16 KB
    int tid = threadIdx.x;
    int row0 = blockIdx.x * 64;

    // stage pre-split h2 (coalesced 16B global loads -> swizzled LDS slots)
    #pragma unroll
    for (int i = 0; i < 4; ++i) {
        int f = i * 256 + tid;            // slot id 0..1023
        int r = f >> 4, sl = f & 15;
        int grow = row0 + r;
        short8 vh = (short8){0,0,0,0,0,0,0,0};
        short8 vl = (short8){0,0,0,0,0,0,0,0};
        if (grow < N) {
            vh = *(const short8*)(h2hi + (size_t)grow * D + sl * 8);
            vl = *(const short8*)(h2lo + (size_t)grow * D + sl * 8);
        }
        int off = r * 128 + ((sl ^ (r & 7)) << 3);
        *(short8*)(shi + off) = vh;
        *(short8*)(slo + off) = vl;
    }
    __syncthreads();

    int w = tid >> 6, lane = tid & 63;
    int lm = lane & 15, lg = lane >> 4;
    int wr0 = (w >> 1) * 32, wc0 = (w & 1) * 64;

    f32x4 acc[2][4];

    layer_bf(shi, slo, w1c, w2c, bc, acc, wr0, wc0, lm, lg);
    __syncthreads();                   // all reads of tiles done
    store_bf(shi, slo, acc, wr0, wc0, lm, lg);
    __syncthreads();

    layer_bf(shi, slo, w1l, w2l, bl, acc, wr0, wc0, lm, lg);

    // direct relu + store to global (64B-granular coalescing per 16-lane group)
    #pragma unroll
    for (int mt = 0; mt < 2; ++mt)
        #pragma unroll
        for (int j = 0; j < 4; ++j) {
            int row = row0 + wr0 + mt * 16 + lg * 4 + j;
            if (row < N) {
                #pragma unroll
                for (int nt = 0; nt < 4; ++nt)
                    out[(size_t)row * D + wc0 + nt * 16 + lm] = fmaxf(acc[mt][nt][j], 0.0f);
            }
        }
}

extern "C" void kernel_launch(void* const* d_in, const int* in_sizes, int n_in,
                              void* d_out, int out_size, void* d_ws, size_t ws_size,
                              hipStream_t stream) {
    const float* x      = (const float*)d_in[0];
    const int*   src    = (const int*)d_in[1];
    const int*   dst    = (const int*)d_in[2];
    const float* wc     = (const float*)d_in[3];
    const float* bc     = (const float*)d_in[4];
    const float* wl     = (const float*)d_in[5];
    const float* bl     = (const float*)d_in[6];
    float* out = (float*)d_out;

    int N = in_sizes[0] / D;
    int E = in_sizes[1];

    // workspace carve-up (256B aligned)
    size_t off = 0;
    auto carve = [&](size_t bytes) -> void* {
        void* p = (char*)d_ws + off;
        off += (bytes + 255) & ~(size_t)255;
        return p;
    };
    unsigned short* xsb       = (unsigned short*)carve((size_t)N * D * 2);
    unsigned short* h2hi      = (unsigned short*)carve((size_t)N * D * 2);
    unsigned short* h2lo      = (unsigned short*)carve((size_t)N * D * 2);
    int*            degp      = (int*)carve((size_t)N * PAD * 4);
    int*            row_start = (int*)carve((size_t)(N + 1) * 4);
    float*          norm      = (float*)carve((size_t)N * 4);
    int*            blockSums = (int*)carve(1024 * 4);
    unsigned short* rank16    = (unsigned short*)carve((size_t)E * 2);
    unsigned short* sorted16  = (unsigned short*)carve((size_t)E * 2);
    unsigned short* w1c = (unsigned short*)carve(16384 * 2);
    unsigned short* w2c = (unsigned short*)carve(16384 * 2);
    unsigned short* w1l = (unsigned short*)carve(16384 * 2);
    unsigned short* w2l = (unsigned short*)carve(16384 * 2);
    (void)ws_size;

    hipMemsetAsync(degp, 0, (size_t)N * PAD * 4, stream);

    int nScanBlocks = (N + SCAN_TILE - 1) / SCAN_TILE;

    prep_w_kernel<<<128, 256, 0, stream>>>(wc, wl, w1c, w2c, w1l, w2l);
    degree_rank_kernel<<<(E + 255) / 256, 256, 0, stream>>>(dst, degp, rank16, E);
    scan_partial_kernel<<<nScanBlocks, 256, 0, stream>>>(degp, blockSums, N);
    scan_blocksums_kernel<<<1, 256, 0, stream>>>(blockSums, nScanBlocks);
    scan_final_kernel<<<nScanBlocks, 256, 0, stream>>>(degp, blockSums, row_start, norm, N, E);
    scatter_kernel<<<(E + 255) / 256, 256, 0, stream>>>(src, dst, rank16, row_start, sorted16, E);
    {
        int total = N * (D / 4);
        scale_kernel<<<(total + 255) / 256, 256, 0, stream>>>(x, norm, xsb, N);
    }
    aggregate_kernel<<<(N + 3) / 4, 256, 0, stream>>>(xsb, sorted16, row_start, norm, h2hi, h2lo, N);
    mlp_mfma_kernel<<<(N + 63) / 64, 256, 0, stream>>>(h2hi, h2lo, w1c, w2c, bc, w1l, w2l, bl, out, N);
}